// Round 1
// baseline (879.215 us; speedup 1.0000x reference)
//
#include <hip/hip_runtime.h>
#include <math.h>

#define Bsz 512
#define Tsz 512
#define Fin 32
#define Hd 64
#define CHUNK 32
#define NCH (Tsz / CHUNK)

typedef float v2f __attribute__((ext_vector_type(2)));

__device__ __forceinline__ float fsig(float x) {
    return 1.0f / (1.0f + __expf(-x));
}
__device__ __forceinline__ float ftanh(float x) {
    float ax = fabsf(x);
    float e  = __expf(-2.0f * ax);
    float t  = (1.0f - e) / (1.0f + e);
    return copysignf(t, x);
}

// ---------------- Layer 0: x[B,T,32] -> h1[B,T,64] ----------------
// One block (512 threads, 8 waves) per batch row. Thread pair (2g, 2g+1)
// splits gate row g's dot product in half (16 x-cols + 32 h-cols each),
// combined with one shfl_xor. This doubles waves/CU (16 vs 8) and halves
// the dependent-FMA chain vs the 256-thread version. The x-dot for step
// t+1 is computed between the gate write and the barrier (it does not
// depend on h), hiding barrier skew. One barrier per step; gates cross
// waves via a parity-double-buffered stride-5 LDS buffer; each wave keeps
// a private h copy and redundantly computes the c-update.
__global__ __launch_bounds__(512, 4)
void lstm_layer0(const float* __restrict__ x,
                 const float4* __restrict__ Wih4,
                 const float4* __restrict__ Whh4,
                 const float* __restrict__ bih,
                 const float* __restrict__ bhh,
                 float* __restrict__ h1out)
{
    __shared__ __align__(16) float xbuf[2][CHUNK * Fin]; // 2 x 4KB
    __shared__ __align__(16) float hbuf[CHUNK * Hd];     // 8KB output staging
    __shared__ __align__(16) float hcopy[8][Hd];         // per-wave private h
    __shared__ float glds[2][Hd * 5];                    // gates, stride 5 (conflict-free)

    const int tid  = threadIdx.x;   // 0..511
    const int lane = tid & 63;
    const int wv   = tid >> 6;      // 0..7
    const int g    = tid >> 1;      // gate row 0..255
    const int half = tid & 1;       // which half of the dot
    const int b    = blockIdx.x;

    // Wih0 [256 x 32] = 8 float4/row; this thread owns 4 (16 cols)
    float4 wih[4];
#pragma unroll
    for (int q = 0; q < 4; ++q) wih[q] = Wih4[g * 8 + half * 4 + q];
    // Whh0 [256 x 64] = 16 float4/row; this thread owns 8 (32 cols)
    float4 whh[8];
#pragma unroll
    for (int q = 0; q < 16 / 2; ++q) whh[q] = Whh4[g * 16 + half * 8 + q];
    const float bias = half ? 0.0f : (bih[g] + bhh[g]);
    const bool is_tanh_gate = ((g >> 6) == 2); // waves 4,5 -> wave-uniform

    float c = 0.0f;
    hcopy[wv][lane] = 0.0f;

    const float4* xsrc = (const float4*)(x + (size_t)b * Tsz * Fin);
    if (tid < 256) ((float4*)xbuf[0])[tid] = xsrc[tid]; // chunk0: 256 float4
    __syncthreads();

    // partial x-dot for one timestep row (this thread's 16 columns)
    auto xdot = [&](const float* xrow_base) -> float {
        const float4* xr = (const float4*)xrow_base + half * 4;
        v2f a0 = {bias, 0.0f}, a1 = {0.0f, 0.0f};
#pragma unroll
        for (int q = 0; q < 4; ++q) {
            float4 xv = xr[q];
            v2f b0 = {xv.x, xv.y}, b1 = {xv.z, xv.w};
            v2f w0 = {wih[q].x, wih[q].y}, w1 = {wih[q].z, wih[q].w};
            a0 = __builtin_elementwise_fma(b0, w0, a0);
            a1 = __builtin_elementwise_fma(b1, w1, a1);
        }
        return (a0.x + a0.y) + (a1.x + a1.y);
    };

    float ax = xdot(&xbuf[0][0]); // t = 0

    for (int ci = 0; ci < NCH; ++ci) {
        const int cur = ci & 1;
        if (ci + 1 < NCH && tid < 256)
            ((float4*)xbuf[cur ^ 1])[tid] = xsrc[(ci + 1) * (CHUNK * Fin / 4) + tid];
#pragma unroll 1
        for (int ct = 0; ct < CHUNK; ++ct) {
            const int t = ci * CHUNK + ct;
            const int p = t & 1;
            // h-dot over this thread's 32 h-columns (2-addr broadcast reads)
            const float4* hr = (const float4*)&hcopy[wv][0] + half * 8;
            v2f a0 = {ax, 0.0f}, a1 = {0.0f, 0.0f};
#pragma unroll
            for (int q = 0; q < 8; ++q) {
                float4 hv = hr[q];
                v2f b0 = {hv.x, hv.y}, b1 = {hv.z, hv.w};
                v2f w0 = {whh[q].x, whh[q].y}, w1 = {whh[q].z, whh[q].w};
                a0 = __builtin_elementwise_fma(b0, w0, a0);
                a1 = __builtin_elementwise_fma(b1, w1, a1);
            }
            float ah = (a0.x + a0.y) + (a1.x + a1.y);
            float a  = ah + __shfl_xor(ah, 1);
            float act = is_tanh_gate ? ftanh(a) : fsig(a);
            if (!half) glds[p][(g & 63) * 5 + (g >> 6)] = act;
            // pipeline: next step's x-partial fills the barrier shadow
            if (ct + 1 < CHUNK)      ax = xdot(&xbuf[cur][(ct + 1) * Fin]);
            else if (ci + 1 < NCH)   ax = xdot(&xbuf[cur ^ 1][0]);
            __syncthreads();
            // every wave redundantly updates its private c/h (identical values)
            float gi = glds[p][lane * 5 + 0];
            float gf = glds[p][lane * 5 + 1];
            float gg = glds[p][lane * 5 + 2];
            float go = glds[p][lane * 5 + 3];
            c = gf * c + gi * gg;
            float h = go * ftanh(c);
            hcopy[wv][lane] = h;
            if (wv == 0) hbuf[ct * Hd + lane] = h;
        }
        __syncthreads(); // hbuf visible to all before flush
        float4* dst = (float4*)(h1out + (size_t)b * Tsz * Hd + (size_t)ci * CHUNK * Hd);
        dst[tid] = ((const float4*)hbuf)[tid]; // 512 float4 = full chunk
    }
}

// ------- Layer 1 + FC: h1[B,T,64] -> out[B] -------
__global__ __launch_bounds__(512, 4)
void lstm_layer1_fc(const float* __restrict__ h1,
                    const float4* __restrict__ Wih4,
                    const float4* __restrict__ Whh4,
                    const float* __restrict__ bih,
                    const float* __restrict__ bhh,
                    const float* __restrict__ fcW,
                    const float* __restrict__ fcb,
                    float* __restrict__ out)
{
    __shared__ __align__(16) float xbuf[2][CHUNK * Hd]; // 2 x 8KB
    __shared__ __align__(16) float hcopy[8][Hd];
    __shared__ float glds[2][Hd * 5];

    const int tid  = threadIdx.x;
    const int lane = tid & 63;
    const int wv   = tid >> 6;
    const int g    = tid >> 1;
    const int half = tid & 1;
    const int b    = blockIdx.x;

    // Wih1 [256 x 64] = 16 float4/row; this thread owns 8 (32 cols)
    float4 wih[8];
#pragma unroll
    for (int q = 0; q < 8; ++q) wih[q] = Wih4[g * 16 + half * 8 + q];
    float4 whh[8];
#pragma unroll
    for (int q = 0; q < 8; ++q) whh[q] = Whh4[g * 16 + half * 8 + q];
    const float bias = half ? 0.0f : (bih[g] + bhh[g]);
    const bool is_tanh_gate = ((g >> 6) == 2);

    float c  = 0.0f;
    float hl = 0.0f;
    hcopy[wv][lane] = 0.0f;

    const float4* xsrc = (const float4*)(h1 + (size_t)b * Tsz * Hd);
    ((float4*)xbuf[0])[tid] = xsrc[tid]; // 512 float4 = chunk0
    __syncthreads();

    auto xdot = [&](const float* xrow_base) -> float {
        const float4* xr = (const float4*)xrow_base + half * 8;
        v2f a0 = {bias, 0.0f}, a1 = {0.0f, 0.0f};
#pragma unroll
        for (int q = 0; q < 8; ++q) {
            float4 xv = xr[q];
            v2f b0 = {xv.x, xv.y}, b1 = {xv.z, xv.w};
            v2f w0 = {wih[q].x, wih[q].y}, w1 = {wih[q].z, wih[q].w};
            a0 = __builtin_elementwise_fma(b0, w0, a0);
            a1 = __builtin_elementwise_fma(b1, w1, a1);
        }
        return (a0.x + a0.y) + (a1.x + a1.y);
    };

    float ax = xdot(&xbuf[0][0]); // t = 0

    for (int ci = 0; ci < NCH; ++ci) {
        const int cur = ci & 1;
        if (ci + 1 < NCH)
            ((float4*)xbuf[cur ^ 1])[tid] = xsrc[(ci + 1) * (CHUNK * Hd / 4) + tid];
#pragma unroll 1
        for (int ct = 0; ct < CHUNK; ++ct) {
            const int t = ci * CHUNK + ct;
            const int p = t & 1;
            const float4* hr = (const float4*)&hcopy[wv][0] + half * 8;
            v2f a0 = {ax, 0.0f}, a1 = {0.0f, 0.0f};
#pragma unroll
            for (int q = 0; q < 8; ++q) {
                float4 hv = hr[q];
                v2f b0 = {hv.x, hv.y}, b1 = {hv.z, hv.w};
                v2f w0 = {whh[q].x, whh[q].y}, w1 = {whh[q].z, whh[q].w};
                a0 = __builtin_elementwise_fma(b0, w0, a0);
                a1 = __builtin_elementwise_fma(b1, w1, a1);
            }
            float ah = (a0.x + a0.y) + (a1.x + a1.y);
            float a  = ah + __shfl_xor(ah, 1);
            float act = is_tanh_gate ? ftanh(a) : fsig(a);
            if (!half) glds[p][(g & 63) * 5 + (g >> 6)] = act;
            if (ct + 1 < CHUNK)      ax = xdot(&xbuf[cur][(ct + 1) * Hd]);
            else if (ci + 1 < NCH)   ax = xdot(&xbuf[cur ^ 1][0]);
            __syncthreads();
            float gi = glds[p][lane * 5 + 0];
            float gf = glds[p][lane * 5 + 1];
            float gg = glds[p][lane * 5 + 2];
            float go = glds[p][lane * 5 + 3];
            c  = gf * c + gi * gg;
            hl = go * ftanh(c);
            hcopy[wv][lane] = hl;
        }
    }
    // fused FC on last h2 (wave 0 only; hl is replicated across waves)
    if (wv == 0) {
        float psum = hl * fcW[lane];
#pragma unroll
        for (int off = 32; off > 0; off >>= 1)
            psum += __shfl_down(psum, off);
        if (lane == 0) out[b] = psum + fcb[0];
    }
}

extern "C" void kernel_launch(void* const* d_in, const int* in_sizes, int n_in,
                              void* d_out, int out_size, void* d_ws, size_t ws_size,
                              hipStream_t stream)
{
    const float* x    = (const float*)d_in[0];
    const float* Wih0 = (const float*)d_in[1];
    const float* Whh0 = (const float*)d_in[2];
    const float* bih0 = (const float*)d_in[3];
    const float* bhh0 = (const float*)d_in[4];
    const float* Wih1 = (const float*)d_in[5];
    const float* Whh1 = (const float*)d_in[6];
    const float* bih1 = (const float*)d_in[7];
    const float* bhh1 = (const float*)d_in[8];
    const float* fcW  = (const float*)d_in[9];
    const float* fcb  = (const float*)d_in[10];
    float* out = (float*)d_out;
    float* h1  = (float*)d_ws; // B*T*H fp32 = 64 MB scratch

    lstm_layer0<<<dim3(Bsz), dim3(512), 0, stream>>>(
        x, (const float4*)Wih0, (const float4*)Whh0, bih0, bhh0, h1);
    lstm_layer1_fc<<<dim3(Bsz), dim3(512), 0, stream>>>(
        h1, (const float4*)Wih1, (const float4*)Whh1, bih1, bhh1, fcW, fcb, out);
}

// Round 3
// 746.128 us; speedup vs baseline: 1.1784x; 1.1784x over previous
//
#include <hip/hip_runtime.h>
#include <math.h>

#define Bsz 512
#define Tsz 512
#define Fin 32
#define Hd 64
#define CHUNK 32
#define NCH (Tsz / CHUNK)

typedef float v2f __attribute__((ext_vector_type(2)));

// v_rcp_f32-based activations (no IEEE div sequence; ~1 ulp)
__device__ __forceinline__ float fsig(float x) {
    return __builtin_amdgcn_rcpf(1.0f + __expf(-x));
}
__device__ __forceinline__ float ftanh(float x) {
    // tanh(x) = 2*sigmoid(2x) - 1
    return fmaf(2.0f, __builtin_amdgcn_rcpf(1.0f + __expf(-2.0f * x)), -1.0f);
}

// Pin a float4's components into arch VGPRs ("v" class excludes AGPRs).
// Tied 32-bit scalar operands are supported (128-bit aggregates are not —
// round-2 compile failure). Volatile asm can't be rematerialized, so the
// compiler cannot park these in AGPRs and pay v_accvgpr_read per use
// (round-0/1 hidden tax: VGPR_Count 60-84 was below the weight footprint).
#define PIN4(v4) \
    asm volatile("" : "+v"((v4).x), "+v"((v4).y), "+v"((v4).z), "+v"((v4).w))

// ---------------- Layer 0: x[B,T,32] -> h1[B,T,64] ----------------
// One block (256 thr, 4 waves) per batch row; thread g owns gate row g with
// weights VGPR-resident. h / x rows broadcast via same-address ds_read_b128.
// One barrier per step; gates cross waves through a parity double-buffered
// stride-5 LDS buffer; each wave keeps a private h copy and redundantly
// computes the c-update (avoids a second barrier). Wave 0 stores h directly
// to global (coalesced b32) - no staging buffer, no per-chunk barrier.
__global__ __launch_bounds__(256, 2)
void lstm_layer0(const float* __restrict__ x,
                 const float4* __restrict__ Wih4,
                 const float4* __restrict__ Whh4,
                 const float* __restrict__ bih,
                 const float* __restrict__ bhh,
                 float* __restrict__ h1out)
{
    __shared__ __align__(16) float xbuf[2][CHUNK * Fin]; // 2 x 4KB
    __shared__ __align__(16) float hcopy[4][Hd];         // per-wave private h
    __shared__ float glds[2][Hd * 5];                    // gates, stride 5

    const int tid  = threadIdx.x;
    const int lane = tid & 63;
    const int wv   = tid >> 6;
    const int wvu  = __builtin_amdgcn_readfirstlane(wv); // SGPR -> s_cbranch
    const int b    = blockIdx.x;

    float4 wih[8];
#pragma unroll
    for (int q = 0; q < 8; ++q) wih[q] = Wih4[tid * 8 + q];
    float4 whh[16];
#pragma unroll
    for (int q = 0; q < 16; ++q) whh[q] = Whh4[tid * 16 + q];
    float bias = bih[tid] + bhh[tid];

    float c = 0.0f;
    hcopy[wv][lane] = 0.0f;

    const float4* xsrc = (const float4*)(x + (size_t)b * Tsz * Fin);
    ((float4*)xbuf[0])[tid] = xsrc[tid];
    float* hout = h1out + (size_t)b * Tsz * Hd + lane;
    __syncthreads();

    for (int ci = 0; ci < NCH; ++ci) {
        const int cur = ci & 1;
        if (ci + 1 < NCH)
            ((float4*)xbuf[cur ^ 1])[tid] = xsrc[(ci + 1) * (CHUNK * Fin / 4) + tid];
        // re-pin each chunk: keeps weights in arch VGPRs across the loop
#pragma unroll
        for (int q = 0; q < 8; ++q)  PIN4(wih[q]);
#pragma unroll
        for (int q = 0; q < 16; ++q) PIN4(whh[q]);
#pragma unroll 1
        for (int ct = 0; ct < CHUNK; ct += 2) {
#pragma unroll
            for (int pp = 0; pp < 2; ++pp) {   // parity compile-time
                const float4* xrow = (const float4*)&xbuf[cur][(ct + pp) * Fin];
                const float4* hrow = (const float4*)&hcopy[wv][0];

                v2f a0 = {bias, 0.0f};
                v2f a1 = {0.0f, 0.0f};
#pragma unroll
                for (int q = 0; q < 8; ++q) {
                    float4 xv = xrow[q];
                    v2f b0 = {xv.x, xv.y}, b1 = {xv.z, xv.w};
                    v2f w0 = {wih[q].x, wih[q].y}, w1 = {wih[q].z, wih[q].w};
                    a0 = __builtin_elementwise_fma(b0, w0, a0);
                    a1 = __builtin_elementwise_fma(b1, w1, a1);
                }
#pragma unroll
                for (int q = 0; q < 16; ++q) {
                    float4 hv = hrow[q];
                    v2f b0 = {hv.x, hv.y}, b1 = {hv.z, hv.w};
                    v2f w0 = {whh[q].x, whh[q].y}, w1 = {whh[q].z, whh[q].w};
                    a0 = __builtin_elementwise_fma(b0, w0, a0);
                    a1 = __builtin_elementwise_fma(b1, w1, a1);
                }
                float a = (a0.x + a0.y) + (a1.x + a1.y);
                if (wvu == 2) glds[pp][lane * 5 + wv] = ftanh(a); // uniform branch
                else          glds[pp][lane * 5 + wv] = fsig(a);
                __syncthreads();
                float gi = glds[pp][lane * 5 + 0];
                float gf = glds[pp][lane * 5 + 1];
                float gg = glds[pp][lane * 5 + 2];
                float go = glds[pp][lane * 5 + 3];
                c = fmaf(gf, c, gi * gg);
                float h = go * ftanh(c);
                hcopy[wv][lane] = h;               // own-wave, in-order LDS
                if (wvu == 0)
                    hout[(size_t)(ci * CHUNK + ct + pp) * Hd] = h;
            }
        }
    }
}

// ------- Layer 1 + FC: h1[B,T,64] -> out[B] -------
__global__ __launch_bounds__(256, 2)
void lstm_layer1_fc(const float* __restrict__ h1,
                    const float4* __restrict__ Wih4,
                    const float4* __restrict__ Whh4,
                    const float* __restrict__ bih,
                    const float* __restrict__ bhh,
                    const float* __restrict__ fcW,
                    const float* __restrict__ fcb,
                    float* __restrict__ out)
{
    __shared__ __align__(16) float xbuf[2][CHUNK * Hd]; // 2 x 8KB
    __shared__ __align__(16) float hcopy[4][Hd];
    __shared__ float glds[2][Hd * 5];

    const int tid  = threadIdx.x;
    const int lane = tid & 63;
    const int wv   = tid >> 6;
    const int wvu  = __builtin_amdgcn_readfirstlane(wv);
    const int b    = blockIdx.x;

    float4 wih[16];
#pragma unroll
    for (int q = 0; q < 16; ++q) wih[q] = Wih4[tid * 16 + q];
    float4 whh[16];
#pragma unroll
    for (int q = 0; q < 16; ++q) whh[q] = Whh4[tid * 16 + q];
    float bias = bih[tid] + bhh[tid];

    float c  = 0.0f;
    float hl = 0.0f;
    hcopy[wv][lane] = 0.0f;

    const float4* xsrc = (const float4*)(h1 + (size_t)b * Tsz * Hd);
    ((float4*)xbuf[0])[tid]       = xsrc[tid];
    ((float4*)xbuf[0])[tid + 256] = xsrc[tid + 256];
    __syncthreads();

    for (int ci = 0; ci < NCH; ++ci) {
        const int cur = ci & 1;
        if (ci + 1 < NCH) {
            ((float4*)xbuf[cur ^ 1])[tid]       = xsrc[(ci + 1) * (CHUNK * Hd / 4) + tid];
            ((float4*)xbuf[cur ^ 1])[tid + 256] = xsrc[(ci + 1) * (CHUNK * Hd / 4) + tid + 256];
        }
#pragma unroll
        for (int q = 0; q < 16; ++q) PIN4(wih[q]);
#pragma unroll
        for (int q = 0; q < 16; ++q) PIN4(whh[q]);
#pragma unroll 1
        for (int ct = 0; ct < CHUNK; ct += 2) {
#pragma unroll
            for (int pp = 0; pp < 2; ++pp) {
                const float4* xrow = (const float4*)&xbuf[cur][(ct + pp) * Hd];
                const float4* hrow = (const float4*)&hcopy[wv][0];

                v2f a0 = {bias, 0.0f};
                v2f a1 = {0.0f, 0.0f};
#pragma unroll
                for (int q = 0; q < 16; ++q) {
                    float4 xv = xrow[q];
                    v2f b0 = {xv.x, xv.y}, b1 = {xv.z, xv.w};
                    v2f w0 = {wih[q].x, wih[q].y}, w1 = {wih[q].z, wih[q].w};
                    a0 = __builtin_elementwise_fma(b0, w0, a0);
                    a1 = __builtin_elementwise_fma(b1, w1, a1);
                }
#pragma unroll
                for (int q = 0; q < 16; ++q) {
                    float4 hv = hrow[q];
                    v2f b0 = {hv.x, hv.y}, b1 = {hv.z, hv.w};
                    v2f w0 = {whh[q].x, whh[q].y}, w1 = {whh[q].z, whh[q].w};
                    a0 = __builtin_elementwise_fma(b0, w0, a0);
                    a1 = __builtin_elementwise_fma(b1, w1, a1);
                }
                float a = (a0.x + a0.y) + (a1.x + a1.y);
                if (wvu == 2) glds[pp][lane * 5 + wv] = ftanh(a);
                else          glds[pp][lane * 5 + wv] = fsig(a);
                __syncthreads();
                float gi = glds[pp][lane * 5 + 0];
                float gf = glds[pp][lane * 5 + 1];
                float gg = glds[pp][lane * 5 + 2];
                float go = glds[pp][lane * 5 + 3];
                c  = fmaf(gf, c, gi * gg);
                hl = go * ftanh(c);
                hcopy[wv][lane] = hl;
            }
        }
    }
    // fused FC on last h2 (wave 0 only; hl is replicated across waves)
    if (wvu == 0) {
        float psum = hl * fcW[lane];
#pragma unroll
        for (int off = 32; off > 0; off >>= 1)
            psum += __shfl_down(psum, off);
        if (lane == 0) out[b] = psum + fcb[0];
    }
}

extern "C" void kernel_launch(void* const* d_in, const int* in_sizes, int n_in,
                              void* d_out, int out_size, void* d_ws, size_t ws_size,
                              hipStream_t stream)
{
    const float* x    = (const float*)d_in[0];
    const float* Wih0 = (const float*)d_in[1];
    const float* Whh0 = (const float*)d_in[2];
    const float* bih0 = (const float*)d_in[3];
    const float* bhh0 = (const float*)d_in[4];
    const float* Wih1 = (const float*)d_in[5];
    const float* Whh1 = (const float*)d_in[6];
    const float* bih1 = (const float*)d_in[7];
    const float* bhh1 = (const float*)d_in[8];
    const float* fcW  = (const float*)d_in[9];
    const float* fcb  = (const float*)d_in[10];
    float* out = (float*)d_out;
    float* h1  = (float*)d_ws; // B*T*H fp32 = 64 MB scratch

    lstm_layer0<<<dim3(Bsz), dim3(256), 0, stream>>>(
        x, (const float4*)Wih0, (const float4*)Whh0, bih0, bhh0, h1);
    lstm_layer1_fc<<<dim3(Bsz), dim3(256), 0, stream>>>(
        h1, (const float4*)Wih1, (const float4*)Whh1, bih1, bhh1, fcW, fcb, out);
}